// Round 9
// baseline (772.075 us; speedup 1.0000x reference)
//
#include <hip/hip_runtime.h>
#include <hip/hip_fp16.h>
#include <math.h>

#define N_NODES 100000
#define N_EDGES 1600000
#define EPRIME  (N_EDGES + N_NODES)
#define NEG_SLOPE 0.2f
#define LOG2E 1.44269504f

// ---------------- edge dtype detect (int64 vs int32) ----------------
__global__ __launch_bounds__(256) void detect_k(const unsigned* __restrict__ w,
                                                unsigned* __restrict__ flag) {
    __shared__ int any;
    if (threadIdx.x == 0) any = 0;
    __syncthreads();
    int nz = 0;
    for (int i = threadIdx.x; i < 1024; i += 256)
        if (w[2 * i + 1] != 0u) nz = 1;
    if (nz) atomicOr(&any, 1);
    __syncthreads();
    if (threadIdx.x == 0) flag[0] = any ? 0u : 1u;  // 1 => int64
}

// ---------------- CSR build ----------------
__global__ __launch_bounds__(256) void init_k(int* __restrict__ counts,
                                              int* __restrict__ fill) {
    int n = blockIdx.x * blockDim.x + threadIdx.x;
    if (n < N_NODES) { counts[n] = 1; fill[n] = 0; }  // 1 = self loop
}

__global__ __launch_bounds__(256) void count_k(const int* __restrict__ ei,
                                               const unsigned* __restrict__ flag,
                                               int* __restrict__ counts) {
    int e = blockIdx.x * blockDim.x + threadIdx.x;
    if (e >= N_EDGES) return;
    int d = flag[0] ? ei[2 * (N_EDGES + e)] : ei[N_EDGES + e];
    atomicAdd(&counts[d], 1);
}

// exclusive scan of counts[0..N-1] -> rowptr[0..N], 1024 elems/block
__global__ __launch_bounds__(256) void scan1_k(const int* __restrict__ counts,
                                               int* __restrict__ rowptr,
                                               int* __restrict__ bsums) {
    __shared__ int s[256];
    int t = threadIdx.x;
    int base = blockIdx.x * 1024 + t * 4;
    int v[4];
#pragma unroll
    for (int j = 0; j < 4; ++j)
        v[j] = (base + j < N_NODES) ? counts[base + j] : 0;
    int tsum = v[0] + v[1] + v[2] + v[3];
    s[t] = tsum;
    __syncthreads();
    for (int off = 1; off < 256; off <<= 1) {
        int x = (t >= off) ? s[t - off] : 0;
        __syncthreads();
        s[t] += x;
        __syncthreads();
    }
    if (t == 255) bsums[blockIdx.x] = s[255];
    int run = s[t] - tsum;  // exclusive prefix for this thread (block-local)
#pragma unroll
    for (int j = 0; j < 4; ++j) {
        if (base + j <= N_NODES) rowptr[base + j] = run;
        run += v[j];
    }
}

__global__ void scan2_k(int* __restrict__ bsums, int nb) {
    if (threadIdx.x == 0 && blockIdx.x == 0) {
        int run = 0;
        for (int i = 0; i < nb; ++i) { int c = bsums[i]; bsums[i] = run; run += c; }
    }
}

__global__ __launch_bounds__(256) void scan3_k(int* __restrict__ rowptr,
                                               const int* __restrict__ bsums) {
    int t = threadIdx.x;
    int base = blockIdx.x * 1024 + t * 4;
    int add = bsums[blockIdx.x];
#pragma unroll
    for (int j = 0; j < 4; ++j)
        if (base + j <= N_NODES) rowptr[base + j] += add;
}

__global__ __launch_bounds__(256) void scatter_k(const int* __restrict__ ei,
                                                 const unsigned* __restrict__ flag,
                                                 const int* __restrict__ rowptr,
                                                 int* __restrict__ fill,
                                                 int* __restrict__ col) {
    int t = blockIdx.x * blockDim.x + threadIdx.x;
    if (t >= EPRIME) return;
    int s, d;
    if (t < N_EDGES) {
        if (flag[0]) { s = ei[2 * t]; d = ei[2 * (N_EDGES + t)]; }
        else         { s = ei[t];     d = ei[N_EDGES + t]; }
    } else {
        s = d = t - N_EDGES;
    }
    int pos = rowptr[d] + atomicAdd(&fill[d], 1);
    col[pos] = s;
}

// ---------------- GEMM1: h1 = x @ W1  (N x 512) @ (512 x 64), h1 stored fp16 ---------
// v6: lane = row, 16 cols/wave (R7 proved no-spill at acc[16], VGPR=20, but
// VALUBusy=26%: per-k mixing of ds_read + s_load forces lgkmcnt(0) drains every
// 32 FMA-cycles). v6 separates the streams: (1) x row hoisted to xr[32] regs
// once per 32-k chunk (pure-DS phase, drained once per 512 FMAs); (2) FMA
// stretch is pure-SMEM-operand (scheduler batches s_loads k-groups ahead);
// (3) T14 split: next chunk's global loads issued before the FMA stretch,
// ds_write after — HBM latency hides under ~1000 cy of FMA.
__global__ __launch_bounds__(256) void gemm1_k(const float* __restrict__ x,
                                               const float* __restrict__ W1,
                                               const float* __restrict__ attl,
                                               const float* __restrict__ attr,
                                               __half* __restrict__ h1,
                                               float* __restrict__ ald,
                                               float* __restrict__ ard) {
    __shared__ float xs[64 * 33];  // 8.4 KB; bank=(row+k)%32 -> 2-way max (free)
    int t = threadIdx.x;
    int w = t >> 6, lane = t & 63;
    int c0 = __builtin_amdgcn_readfirstlane(w * 16);  // wave-uniform col base
    int row0 = blockIdx.x * 64;
    int myrow = row0 + lane;
    bool valid = myrow < N_NODES;

    // staging map: thread t handles float4 slots t and t+256 of the
    // 64x32-float chunk (512 float4); slot f -> row f>>3, quad f&7 (coalesced).
    int ra = t >> 3, qa = t & 7;
    int rb = (t + 256) >> 3, qb = t & 7;  // (t+256)&7 == t&7
    bool va = (row0 + ra) < N_NODES, vb = (row0 + rb) < N_NODES;
    const float4* x4 = (const float4*)x;

    float4 sa = make_float4(0.f, 0.f, 0.f, 0.f);
    float4 sb = make_float4(0.f, 0.f, 0.f, 0.f);
    if (va) sa = x4[(size_t)(row0 + ra) * 128 + qa];
    if (vb) sb = x4[(size_t)(row0 + rb) * 128 + qb];
    {
        float* d0 = &xs[ra * 33 + qa * 4];
        float* d1 = &xs[rb * 33 + qb * 4];
        d0[0] = sa.x; d0[1] = sa.y; d0[2] = sa.z; d0[3] = sa.w;
        d1[0] = sb.x; d1[1] = sb.y; d1[2] = sb.z; d1[3] = sb.w;
    }
    __syncthreads();

    float acc[16];
#pragma unroll
    for (int c = 0; c < 16; ++c) acc[c] = 0.f;

    for (int ci = 0; ci < 16; ++ci) {
        int kc = ci * 32;
        // T14: issue next chunk's global loads now; consumed after the barrier.
        if (ci < 15) {
            int kq = ((kc + 32) >> 2);
            sa = va ? x4[(size_t)(row0 + ra) * 128 + kq + qa] : make_float4(0.f, 0.f, 0.f, 0.f);
            sb = vb ? x4[(size_t)(row0 + rb) * 128 + kq + qb] : make_float4(0.f, 0.f, 0.f, 0.f);
        }
        // pure-DS phase: hoist my x row chunk into registers (conflict-free)
        float xr[32];
#pragma unroll
        for (int k = 0; k < 32; ++k) xr[k] = xs[lane * 33 + k];
        // pure-SMEM FMA stretch: W1 row is wave-uniform -> s_load operands
#pragma unroll
        for (int k = 0; k < 32; ++k) {
            const float* wr = &W1[(size_t)(kc + k) * 64 + c0];
#pragma unroll
            for (int c = 0; c < 16; ++c)
                acc[c] = fmaf(xr[k], wr[c], acc[c]);
        }
        if (ci < 15) {
            __syncthreads();  // all waves done reading xs for chunk ci
            float* d0 = &xs[ra * 33 + qa * 4];
            float* d1 = &xs[rb * 33 + qb * 4];
            d0[0] = sa.x; d0[1] = sa.y; d0[2] = sa.z; d0[3] = sa.w;
            d1[0] = sb.x; d1[1] = sb.y; d1[2] = sb.z; d1[3] = sb.w;
            __syncthreads();
        }
    }

    if (valid) {
        // pack 16 cols to fp16 (32 B) without address-taking any local array
        unsigned u0 = __builtin_bit_cast(unsigned, __floats2half2_rn(acc[0],  acc[1]));
        unsigned u1 = __builtin_bit_cast(unsigned, __floats2half2_rn(acc[2],  acc[3]));
        unsigned u2 = __builtin_bit_cast(unsigned, __floats2half2_rn(acc[4],  acc[5]));
        unsigned u3 = __builtin_bit_cast(unsigned, __floats2half2_rn(acc[6],  acc[7]));
        unsigned u4 = __builtin_bit_cast(unsigned, __floats2half2_rn(acc[8],  acc[9]));
        unsigned u5 = __builtin_bit_cast(unsigned, __floats2half2_rn(acc[10], acc[11]));
        unsigned u6 = __builtin_bit_cast(unsigned, __floats2half2_rn(acc[12], acc[13]));
        unsigned u7 = __builtin_bit_cast(unsigned, __floats2half2_rn(acc[14], acc[15]));
        float4* dst = (float4*)(h1 + (size_t)myrow * 64 + c0);
        dst[0] = make_float4(__uint_as_float(u0), __uint_as_float(u1),
                             __uint_as_float(u2), __uint_as_float(u3));
        dst[1] = make_float4(__uint_as_float(u4), __uint_as_float(u5),
                             __uint_as_float(u6), __uint_as_float(u7));

        // att dots for this wave's 2 heads (row-local, scalar stores)
#pragma unroll
        for (int h = 0; h < 2; ++h) {
            float vl = 0.f, vr = 0.f;
#pragma unroll
            for (int cc = 0; cc < 8; ++cc) {
                vl = fmaf(acc[h * 8 + cc], attl[c0 + h * 8 + cc], vl);
                vr = fmaf(acc[h * 8 + cc], attr[c0 + h * 8 + cc], vr);
            }
            ald[(size_t)myrow * 8 + (c0 >> 3) + h] = vl * LOG2E;
            ard[(size_t)myrow * 8 + (c0 >> 3) + h] = vr * LOG2E;
        }
    }
}

// ---------------- attn1: one wave per node, lane = channel (64ch, fp16 gathers) -------
// exp2-domain online softmax, defer-max, 2-edge unrolled pipeline (depth-2 prefetch).
__global__ __launch_bounds__(256) void attn1_k(const __half* __restrict__ h1,
                                               const int* __restrict__ rowptr,
                                               const int* __restrict__ col,
                                               const float* __restrict__ ald,
                                               const float* __restrict__ ard,
                                               const float* __restrict__ b1,
                                               float* __restrict__ hout) {
    int wid = (blockIdx.x * blockDim.x + threadIdx.x) >> 6;  // node
    int lane = threadIdx.x & 63;
    if (wid >= N_NODES) return;
    int head = lane >> 3;
    float xi = __half2float(h1[(size_t)wid * 64 + lane]);
    float ardi = ard[wid * 8 + head];
    int beg = rowptr[wid], end = rowptr[wid + 1];
    int last = end - 1;

    // pipeline prime: edges beg, beg+1
    int s0 = col[beg];
    int s1 = col[min(beg + 1, last)];
    float xj0 = __half2float(h1[(size_t)s0 * 64 + lane]);
    float aj0 = ald[s0 * 8 + head];
    float xj1 = __half2float(h1[(size_t)s1 * 64 + lane]);
    float aj1 = ald[s1 * 8 + head];

    float m2 = -INFINITY, lsum = 0.f, accv = 0.f;
    for (int e = beg; e < end; e += 2) {
        // prefetch e+2, e+3 (clamped; harmless dup loads near tail)
        int sp0 = col[min(e + 2, last)];
        int sp1 = col[min(e + 3, last)];
        float xn0 = __half2float(h1[(size_t)sp0 * 64 + lane]);
        float an0 = ald[sp0 * 8 + head];
        float xn1 = __half2float(h1[(size_t)sp1 * 64 + lane]);
        float an1 = ald[sp1 * 8 + head];

        float dot0 = xi * xj0, dot1 = xi * xj1;
        dot0 += __shfl_xor(dot0, 1); dot1 += __shfl_xor(dot1, 1);
        dot0 += __shfl_xor(dot0, 2); dot1 += __shfl_xor(dot1, 2);
        dot0 += __shfl_xor(dot0, 4); dot1 += __shfl_xor(dot1, 4);
        float sig0 = __builtin_amdgcn_rcpf(1.f + __builtin_amdgcn_exp2f(dot0 * -LOG2E));
        float sig1 = __builtin_amdgcn_rcpf(1.f + __builtin_amdgcn_exp2f(dot1 * -LOG2E));
        float g0 = (aj0 + ardi) * sig0;
        float g1 = (aj1 + ardi) * sig1;
        float a20 = fmaxf(g0, NEG_SLOPE * g0);
        float a21 = (e + 1 < end) ? fmaxf(g1, NEG_SLOPE * g1) : -INFINITY;
        float pm = fmaxf(a20, a21);
        if (__any(pm > m2 + 11.5f)) {
            float mn = fmaxf(m2, pm);
            float so = __builtin_amdgcn_exp2f(m2 - mn);
            lsum *= so; accv *= so; m2 = mn;
        }
        float p0 = __builtin_amdgcn_exp2f(a20 - m2);
        float p1 = __builtin_amdgcn_exp2f(a21 - m2);
        lsum += p0 + p1;
        accv += p0 * xj0 + p1 * xj1;
        xj0 = xn0; aj0 = an0; xj1 = xn1; aj1 = an1;
    }
    float o = accv * __builtin_amdgcn_rcpf(lsum) + b1[lane];
    o = o > 0.f ? o : (__builtin_amdgcn_exp2f(o * LOG2E) - 1.f);  // ELU
    hout[(size_t)wid * 64 + lane] = o;
}

// ---------------- GEMM2: h2 = hout @ W2  (N x 64) @ (64 x 128), h2 stored fp16x2 ------
// + fused per-node att dots for layer 2.
__global__ __launch_bounds__(256) void gemm2_k(const float* __restrict__ h,
                                               const float* __restrict__ W2,
                                               const float* __restrict__ attl,
                                               const float* __restrict__ attr,
                                               __half2* __restrict__ h2,
                                               float* __restrict__ ald,
                                               float* __restrict__ ard) {
    __shared__ float xs[32 * 64];
    int t = threadIdx.x;
    int row0 = blockIdx.x * 32;
    for (int i = t; i < 32 * 16; i += 256) {
        int r = i >> 4, q = i & 15;
        int gr = row0 + r;
        float4 v = make_float4(0.f, 0.f, 0.f, 0.f);
        if (gr < N_NODES) v = ((const float4*)h)[(size_t)gr * 16 + q];
        ((float4*)xs)[r * 16 + q] = v;
    }
    __syncthreads();
    int w = t >> 6, lane = t & 63;
    int r0 = w * 8;
    float2 acc[8];
#pragma unroll
    for (int r = 0; r < 8; ++r) acc[r] = make_float2(0.f, 0.f);
    for (int k = 0; k < 64; ++k) {
        float2 wv = ((const float2*)W2)[k * 64 + lane];
#pragma unroll
        for (int r = 0; r < 8; ++r) {
            float xv = xs[(r0 + r) * 64 + k];
            acc[r].x += xv * wv.x;
            acc[r].y += xv * wv.y;
        }
    }
    float2 al = ((const float2*)attl)[lane];
    float2 ar = ((const float2*)attr)[lane];
#pragma unroll
    for (int r = 0; r < 8; ++r) {
        int gr = row0 + r0 + r;
        float vl = acc[r].x * al.x + acc[r].y * al.y;
        float vr = acc[r].x * ar.x + acc[r].y * ar.y;
        vl += __shfl_xor(vl, 1); vr += __shfl_xor(vr, 1);
        vl += __shfl_xor(vl, 2); vr += __shfl_xor(vr, 2);
        vl += __shfl_xor(vl, 4); vr += __shfl_xor(vr, 4);
        if (gr < N_NODES) {
            h2[(size_t)gr * 64 + lane] = __floats2half2_rn(acc[r].x, acc[r].y);
            if ((lane & 7) == 0) {
                ald[gr * 8 + (lane >> 3)] = vl * LOG2E;
                ard[gr * 8 + (lane >> 3)] = vr * LOG2E;
            }
        }
    }
}

// ---------------- attn2: one wave per node, 2 ch/lane (fp16x2 gathers) ----------------
// online softmax (exp2, defer-max), 2-edge pipeline + head mean + bias + log_softmax
__global__ __launch_bounds__(256) void attn2_k(const __half2* __restrict__ h2,
                                               const int* __restrict__ rowptr,
                                               const int* __restrict__ col,
                                               const float* __restrict__ ald,
                                               const float* __restrict__ ard,
                                               const float* __restrict__ b2,
                                               float* __restrict__ out) {
    int wid = (blockIdx.x * blockDim.x + threadIdx.x) >> 6;  // node
    int lane = threadIdx.x & 63;
    if (wid >= N_NODES) return;
    int head = lane >> 3;
    float2 xi = __half22float2(h2[(size_t)wid * 64 + lane]);
    float ardi = ard[wid * 8 + head];
    int beg = rowptr[wid], end = rowptr[wid + 1];
    int last = end - 1;

    int s0 = col[beg];
    int s1 = col[min(beg + 1, last)];
    float2 xj0 = __half22float2(h2[(size_t)s0 * 64 + lane]);
    float aj0 = ald[s0 * 8 + head];
    float2 xj1 = __half22float2(h2[(size_t)s1 * 64 + lane]);
    float aj1 = ald[s1 * 8 + head];

    float m2 = -INFINITY, lsum = 0.f;
    float2 acc = make_float2(0.f, 0.f);
    for (int e = beg; e < end; e += 2) {
        int sp0 = col[min(e + 2, last)];
        int sp1 = col[min(e + 3, last)];
        float2 xn0 = __half22float2(h2[(size_t)sp0 * 64 + lane]);
        float an0 = ald[sp0 * 8 + head];
        float2 xn1 = __half22float2(h2[(size_t)sp1 * 64 + lane]);
        float an1 = ald[sp1 * 8 + head];

        float dot0 = xi.x * xj0.x + xi.y * xj0.y;
        float dot1 = xi.x * xj1.x + xi.y * xj1.y;
        dot0 += __shfl_xor(dot0, 1); dot1 += __shfl_xor(dot1, 1);
        dot0 += __shfl_xor(dot0, 2); dot1 += __shfl_xor(dot1, 2);
        dot0 += __shfl_xor(dot0, 4); dot1 += __shfl_xor(dot1, 4);
        float sig0 = __builtin_amdgcn_rcpf(1.f + __builtin_amdgcn_exp2f(dot0 * -LOG2E));
        float sig1 = __builtin_amdgcn_rcpf(1.f + __builtin_amdgcn_exp2f(dot1 * -LOG2E));
        float g0 = (aj0 + ardi) * sig0;
        float g1 = (aj1 + ardi) * sig1;
        float a20 = fmaxf(g0, NEG_SLOPE * g0);
        float a21 = (e + 1 < end) ? fmaxf(g1, NEG_SLOPE * g1) : -INFINITY;
        float pm = fmaxf(a20, a21);
        if (__any(pm > m2 + 11.5f)) {
            float mn = fmaxf(m2, pm);
            float so = __builtin_amdgcn_exp2f(m2 - mn);
            lsum *= so; acc.x *= so; acc.y *= so; m2 = mn;
        }
        float p0 = __builtin_amdgcn_exp2f(a20 - m2);
        float p1 = __builtin_amdgcn_exp2f(a21 - m2);
        lsum += p0 + p1;
        acc.x += p0 * xj0.x + p1 * xj1.x;
        acc.y += p0 * xj0.y + p1 * xj1.y;
        xj0 = xn0; aj0 = an0; xj1 = xn1; aj1 = an1;
    }
    float rl = __builtin_amdgcn_rcpf(lsum);
    float ox = acc.x * rl;
    float oy = acc.y * rl;
    // mean over heads: lanes with equal (l&7) hold same channel pair across heads
    ox += __shfl_xor(ox, 8); oy += __shfl_xor(oy, 8);
    ox += __shfl_xor(ox, 16); oy += __shfl_xor(oy, 16);
    ox += __shfl_xor(ox, 32); oy += __shfl_xor(oy, 32);
    int c2 = (lane & 7) * 2;
    float vx = ox * 0.125f + b2[c2];
    float vy = oy * 0.125f + b2[c2 + 1];
    // log_softmax across 16 channels held by the 8-lane group (2 per lane)
    float mx = fmaxf(vx, vy);
    mx = fmaxf(mx, __shfl_xor(mx, 1));
    mx = fmaxf(mx, __shfl_xor(mx, 2));
    mx = fmaxf(mx, __shfl_xor(mx, 4));
    float se = __expf(vx - mx) + __expf(vy - mx);
    se += __shfl_xor(se, 1); se += __shfl_xor(se, 2); se += __shfl_xor(se, 4);
    float ls = __logf(se);
    if (lane < 8)
        ((float2*)out)[(size_t)wid * 8 + lane] = make_float2(vx - mx - ls, vy - mx - ls);
}

// ---------------- host ----------------
extern "C" void kernel_launch(void* const* d_in, const int* in_sizes, int n_in,
                              void* d_out, int out_size, void* d_ws, size_t ws_size,
                              hipStream_t stream) {
    const float* x     = (const float*)d_in[0];
    const int*   ei    = (const int*)d_in[1];
    const float* W1    = (const float*)d_in[2];
    const float* attl1 = (const float*)d_in[3];
    const float* attr1 = (const float*)d_in[4];
    const float* b1    = (const float*)d_in[5];
    const float* W2    = (const float*)d_in[6];
    const float* attl2 = (const float*)d_in[7];
    const float* attr2 = (const float*)d_in[8];
    const float* b2    = (const float*)d_in[9];
    float* out = (float*)d_out;

    char* ws = (char*)d_ws;
    size_t off = 0;
    auto alloc = [&](size_t bytes) {
        size_t o = off;
        off += (bytes + 255) & ~(size_t)255;
        return o;
    };
    size_t o_flag   = alloc(4);
    size_t o_counts = alloc((size_t)N_NODES * 4);
    size_t o_fill   = alloc((size_t)N_NODES * 4);
    size_t o_rowptr = alloc((size_t)(N_NODES + 1) * 4);
    size_t o_bsums  = alloc(1024 * 4);
    size_t o_col    = alloc((size_t)EPRIME * 4);
    size_t o_h1     = alloc((size_t)N_NODES * 64 * 4);   // (over-alloc; h1 is fp16 now)
    size_t o_hout   = alloc((size_t)N_NODES * 64 * 4);
    size_t o_h2     = alloc((size_t)N_NODES * 128 * 4);  // (over-alloc; h2 is fp16 now)

    size_t aldsz = ((size_t)N_NODES * 8 * 4 + 255) & ~(size_t)255;
    // layer-1 att dots alias the h2 region (h2 written later, after attn1 reads these)
    size_t o_ald1 = o_h2;
    size_t o_ard1 = o_h2 + aldsz;
    // layer-2 att dots alias the h1 region (h1 dead after attn1)
    size_t o_ald2 = o_h1;
    size_t o_ard2 = o_h1 + aldsz;

    unsigned* flag = (unsigned*)(ws + o_flag);
    int* counts = (int*)(ws + o_counts);
    int* fill   = (int*)(ws + o_fill);
    int* rowptr = (int*)(ws + o_rowptr);
    int* bsums  = (int*)(ws + o_bsums);
    int* col    = (int*)(ws + o_col);
    __half* h1  = (__half*)(ws + o_h1);
    float* hout = (float*)(ws + o_hout);
    __half2* h2 = (__half2*)(ws + o_h2);
    float* ald1 = (float*)(ws + o_ald1);
    float* ard1 = (float*)(ws + o_ard1);
    float* ald2 = (float*)(ws + o_ald2);
    float* ard2 = (float*)(ws + o_ard2);

    int nscan = (N_NODES + 1 + 1023) / 1024;  // 99

    hipLaunchKernelGGL(detect_k, dim3(1), dim3(256), 0, stream, (const unsigned*)ei, flag);
    hipLaunchKernelGGL(init_k, dim3((N_NODES + 255) / 256), dim3(256), 0, stream, counts, fill);
    hipLaunchKernelGGL(count_k, dim3((N_EDGES + 255) / 256), dim3(256), 0, stream, ei, flag, counts);
    hipLaunchKernelGGL(scan1_k, dim3(nscan), dim3(256), 0, stream, counts, rowptr, bsums);
    hipLaunchKernelGGL(scan2_k, dim3(1), dim3(64), 0, stream, bsums, nscan);
    hipLaunchKernelGGL(scan3_k, dim3(nscan), dim3(256), 0, stream, rowptr, bsums);
    hipLaunchKernelGGL(scatter_k, dim3((EPRIME + 255) / 256), dim3(256), 0, stream,
                       ei, flag, rowptr, fill, col);
    hipLaunchKernelGGL(gemm1_k, dim3((N_NODES + 63) / 64), dim3(256), 0, stream,
                       x, W1, attl1, attr1, h1, ald1, ard1);
    hipLaunchKernelGGL(attn1_k, dim3((N_NODES + 3) / 4), dim3(256), 0, stream,
                       h1, rowptr, col, ald1, ard1, b1, hout);
    hipLaunchKernelGGL(gemm2_k, dim3((N_NODES + 31) / 32), dim3(256), 0, stream,
                       hout, W2, attl2, attr2, h2, ald2, ard2);
    hipLaunchKernelGGL(attn2_k, dim3((N_NODES + 3) / 4), dim3(256), 0, stream,
                       h2, rowptr, col, ald2, ard2, b2, out);
}

// Round 10
// 528.477 us; speedup vs baseline: 1.4609x; 1.4609x over previous
//
#include <hip/hip_runtime.h>
#include <hip/hip_fp16.h>
#include <math.h>

#define N_NODES 100000
#define N_EDGES 1600000
#define EPRIME  (N_EDGES + N_NODES)
#define NEG_SLOPE 0.2f
#define LOG2E 1.44269504f

typedef _Float16 f16x8 __attribute__((ext_vector_type(8)));
typedef float f32x4 __attribute__((ext_vector_type(4)));

// ---------------- edge dtype detect (int64 vs int32) ----------------
__global__ __launch_bounds__(256) void detect_k(const unsigned* __restrict__ w,
                                                unsigned* __restrict__ flag) {
    __shared__ int any;
    if (threadIdx.x == 0) any = 0;
    __syncthreads();
    int nz = 0;
    for (int i = threadIdx.x; i < 1024; i += 256)
        if (w[2 * i + 1] != 0u) nz = 1;
    if (nz) atomicOr(&any, 1);
    __syncthreads();
    if (threadIdx.x == 0) flag[0] = any ? 0u : 1u;  // 1 => int64
}

// ---------------- CSR build ----------------
__global__ __launch_bounds__(256) void init_k(int* __restrict__ counts,
                                              int* __restrict__ fill) {
    int n = blockIdx.x * blockDim.x + threadIdx.x;
    if (n < N_NODES) { counts[n] = 1; fill[n] = 0; }  // 1 = self loop
}

__global__ __launch_bounds__(256) void count_k(const int* __restrict__ ei,
                                               const unsigned* __restrict__ flag,
                                               int* __restrict__ counts) {
    int e = blockIdx.x * blockDim.x + threadIdx.x;
    if (e >= N_EDGES) return;
    int d = flag[0] ? ei[2 * (N_EDGES + e)] : ei[N_EDGES + e];
    atomicAdd(&counts[d], 1);
}

// exclusive scan of counts[0..N-1] -> rowptr[0..N], 1024 elems/block
__global__ __launch_bounds__(256) void scan1_k(const int* __restrict__ counts,
                                               int* __restrict__ rowptr,
                                               int* __restrict__ bsums) {
    __shared__ int s[256];
    int t = threadIdx.x;
    int base = blockIdx.x * 1024 + t * 4;
    int v[4];
#pragma unroll
    for (int j = 0; j < 4; ++j)
        v[j] = (base + j < N_NODES) ? counts[base + j] : 0;
    int tsum = v[0] + v[1] + v[2] + v[3];
    s[t] = tsum;
    __syncthreads();
    for (int off = 1; off < 256; off <<= 1) {
        int x = (t >= off) ? s[t - off] : 0;
        __syncthreads();
        s[t] += x;
        __syncthreads();
    }
    if (t == 255) bsums[blockIdx.x] = s[255];
    int run = s[t] - tsum;  // exclusive prefix for this thread (block-local)
#pragma unroll
    for (int j = 0; j < 4; ++j) {
        if (base + j <= N_NODES) rowptr[base + j] = run;
        run += v[j];
    }
}

__global__ void scan2_k(int* __restrict__ bsums, int nb) {
    if (threadIdx.x == 0 && blockIdx.x == 0) {
        int run = 0;
        for (int i = 0; i < nb; ++i) { int c = bsums[i]; bsums[i] = run; run += c; }
    }
}

__global__ __launch_bounds__(256) void scan3_k(int* __restrict__ rowptr,
                                               const int* __restrict__ bsums) {
    int t = threadIdx.x;
    int base = blockIdx.x * 1024 + t * 4;
    int add = bsums[blockIdx.x];
#pragma unroll
    for (int j = 0; j < 4; ++j)
        if (base + j <= N_NODES) rowptr[base + j] += add;
}

__global__ __launch_bounds__(256) void scatter_k(const int* __restrict__ ei,
                                                 const unsigned* __restrict__ flag,
                                                 const int* __restrict__ rowptr,
                                                 int* __restrict__ fill,
                                                 int* __restrict__ col) {
    int t = blockIdx.x * blockDim.x + threadIdx.x;
    if (t >= EPRIME) return;
    int s, d;
    if (t < N_EDGES) {
        if (flag[0]) { s = ei[2 * t]; d = ei[2 * (N_EDGES + t)]; }
        else         { s = ei[t];     d = ei[N_EDGES + t]; }
    } else {
        s = d = t - N_EDGES;
    }
    int pos = rowptr[d] + atomicAdd(&fill[d], 1);
    col[pos] = s;
}

// ---------------- W1 -> fp16 fragment-order pre-swizzle ----------------
// Slot idx = ((ks*4 + nt)*64 + lane)*8 + j  holds  W1[k][c] with
// k = ks*32 + 8*(lane>>4) + j,  c = nt*16 + (lane&15).
// A-frag uses the SAME k-pattern, so the MFMA dot is correct for any
// within-instruction K-ordering (K-permutation invariance).
__global__ __launch_bounds__(256) void w1cvt_k(const float* __restrict__ W1,
                                               _Float16* __restrict__ W1f) {
    int idx = blockIdx.x * 256 + threadIdx.x;
    if (idx >= 512 * 64) return;
    int j    = idx & 7;
    int lane = (idx >> 3) & 63;
    int nt   = (idx >> 9) & 3;
    int ks   = idx >> 11;
    int k = ks * 32 + (lane >> 4) * 8 + j;
    int c = nt * 16 + (lane & 15);
    W1f[idx] = (_Float16)W1[k * 64 + c];
}

// ---------------- GEMM1 (MFMA): h1 = x @ W1, h1 fp16 + fused att dots --------
// v7: mfma_f32_16x16x32_f16. One wave = 16 rows x 64 cols (4 acc frags),
// K=512 in 16 steps. A loaded direct from global (fp32 -> cvt f16), B from
// pre-swizzled W1f (one coalesced 16B load per tile). No LDS, no barriers,
// no scalar-operand FMA pipeline — replaces the VALU structure that
// plateaued at ~190-230us across R5-R8 (spill / lgkmcnt / barrier limits).
// D layout (m89-verified): row=(lane>>4)*4+reg, col=lane&15.
__global__ __launch_bounds__(256) void gemm1_k(const float* __restrict__ x,
                                               const _Float16* __restrict__ W1f,
                                               const float* __restrict__ attl,
                                               const float* __restrict__ attr,
                                               __half* __restrict__ h1,
                                               float* __restrict__ ald,
                                               float* __restrict__ ard) {
    int t = threadIdx.x;
    int w = t >> 6, l = t & 63;
    int rw0 = blockIdx.x * 64 + w * 16;
    int arow = rw0 + (l & 15);
    if (arow >= N_NODES) arow = N_NODES - 1;  // clamp; OOB outputs are guarded
    int kg = l >> 4;                           // k-group 0..3
    const float4* x4 = (const float4*)(x + (size_t)arow * 512);
    const f16x8* w8 = (const f16x8*)W1f;

    f32x4 acc0 = {0.f, 0.f, 0.f, 0.f};
    f32x4 acc1 = {0.f, 0.f, 0.f, 0.f};
    f32x4 acc2 = {0.f, 0.f, 0.f, 0.f};
    f32x4 acc3 = {0.f, 0.f, 0.f, 0.f};

#pragma unroll 4
    for (int ks = 0; ks < 16; ++ks) {
        float4 a0 = x4[ks * 8 + kg * 2];
        float4 a1 = x4[ks * 8 + kg * 2 + 1];
        f16x8 af;
        af[0] = (_Float16)a0.x; af[1] = (_Float16)a0.y;
        af[2] = (_Float16)a0.z; af[3] = (_Float16)a0.w;
        af[4] = (_Float16)a1.x; af[5] = (_Float16)a1.y;
        af[6] = (_Float16)a1.z; af[7] = (_Float16)a1.w;
        f16x8 b0 = w8[(ks * 4 + 0) * 64 + l];
        f16x8 b1 = w8[(ks * 4 + 1) * 64 + l];
        f16x8 b2 = w8[(ks * 4 + 2) * 64 + l];
        f16x8 b3 = w8[(ks * 4 + 3) * 64 + l];
        acc0 = __builtin_amdgcn_mfma_f32_16x16x32_f16(af, b0, acc0, 0, 0, 0);
        acc1 = __builtin_amdgcn_mfma_f32_16x16x32_f16(af, b1, acc1, 0, 0, 0);
        acc2 = __builtin_amdgcn_mfma_f32_16x16x32_f16(af, b2, acc2, 0, 0, 0);
        acc3 = __builtin_amdgcn_mfma_f32_16x16x32_f16(af, b3, acc3, 0, 0, 0);
    }

    // epilogue: lane holds D rows rw0+(l>>4)*4+reg, cols nt*16+(l&15)
    int col = l & 15;
    int hi = col >> 3;  // head parity within a 16-col tile
    float al0 = attl[col], al1 = attl[16 + col], al2 = attl[32 + col], al3 = attl[48 + col];
    float ar0 = attr[col], ar1 = attr[16 + col], ar2 = attr[32 + col], ar3 = attr[48 + col];

#pragma unroll
    for (int reg = 0; reg < 4; ++reg) {
        int grow = rw0 + (l >> 4) * 4 + reg;
        bool v = grow < N_NODES;
        float c0 = acc0[reg], c1 = acc1[reg], c2 = acc2[reg], c3 = acc3[reg];
        if (v) {
            __half* hp = h1 + (size_t)grow * 64;
            hp[col]      = __float2half_rn(c0);
            hp[16 + col] = __float2half_rn(c1);
            hp[32 + col] = __float2half_rn(c2);
            hp[48 + col] = __float2half_rn(c3);
        }
        // att dots: head = nt*2 + hi; 8 lanes (xor 1,2,4) hold that head's cols
        float vl0 = c0 * al0, vl1 = c1 * al1, vl2 = c2 * al2, vl3 = c3 * al3;
        float vr0 = c0 * ar0, vr1 = c1 * ar1, vr2 = c2 * ar2, vr3 = c3 * ar3;
        vl0 += __shfl_xor(vl0, 1); vl1 += __shfl_xor(vl1, 1);
        vl2 += __shfl_xor(vl2, 1); vl3 += __shfl_xor(vl3, 1);
        vr0 += __shfl_xor(vr0, 1); vr1 += __shfl_xor(vr1, 1);
        vr2 += __shfl_xor(vr2, 1); vr3 += __shfl_xor(vr3, 1);
        vl0 += __shfl_xor(vl0, 2); vl1 += __shfl_xor(vl1, 2);
        vl2 += __shfl_xor(vl2, 2); vl3 += __shfl_xor(vl3, 2);
        vr0 += __shfl_xor(vr0, 2); vr1 += __shfl_xor(vr1, 2);
        vr2 += __shfl_xor(vr2, 2); vr3 += __shfl_xor(vr3, 2);
        vl0 += __shfl_xor(vl0, 4); vl1 += __shfl_xor(vl1, 4);
        vl2 += __shfl_xor(vl2, 4); vl3 += __shfl_xor(vl3, 4);
        vr0 += __shfl_xor(vr0, 4); vr1 += __shfl_xor(vr1, 4);
        vr2 += __shfl_xor(vr2, 4); vr3 += __shfl_xor(vr3, 4);
        if (v && (l & 7) == 0) {
            float* alp = ald + (size_t)grow * 8;
            float* arp = ard + (size_t)grow * 8;
            alp[0 + hi] = vl0 * LOG2E; alp[2 + hi] = vl1 * LOG2E;
            alp[4 + hi] = vl2 * LOG2E; alp[6 + hi] = vl3 * LOG2E;
            arp[0 + hi] = vr0 * LOG2E; arp[2 + hi] = vr1 * LOG2E;
            arp[4 + hi] = vr2 * LOG2E; arp[6 + hi] = vr3 * LOG2E;
        }
    }
}

// ---------------- attn1: one wave per node, lane = channel (64ch, fp16 gathers) -------
// exp2-domain online softmax, defer-max, 2-edge unrolled pipeline (depth-2 prefetch).
__global__ __launch_bounds__(256) void attn1_k(const __half* __restrict__ h1,
                                               const int* __restrict__ rowptr,
                                               const int* __restrict__ col,
                                               const float* __restrict__ ald,
                                               const float* __restrict__ ard,
                                               const float* __restrict__ b1,
                                               float* __restrict__ hout) {
    int wid = (blockIdx.x * blockDim.x + threadIdx.x) >> 6;  // node
    int lane = threadIdx.x & 63;
    if (wid >= N_NODES) return;
    int head = lane >> 3;
    float xi = __half2float(h1[(size_t)wid * 64 + lane]);
    float ardi = ard[wid * 8 + head];
    int beg = rowptr[wid], end = rowptr[wid + 1];
    int last = end - 1;

    // pipeline prime: edges beg, beg+1
    int s0 = col[beg];
    int s1 = col[min(beg + 1, last)];
    float xj0 = __half2float(h1[(size_t)s0 * 64 + lane]);
    float aj0 = ald[s0 * 8 + head];
    float xj1 = __half2float(h1[(size_t)s1 * 64 + lane]);
    float aj1 = ald[s1 * 8 + head];

    float m2 = -INFINITY, lsum = 0.f, accv = 0.f;
    for (int e = beg; e < end; e += 2) {
        // prefetch e+2, e+3 (clamped; harmless dup loads near tail)
        int sp0 = col[min(e + 2, last)];
        int sp1 = col[min(e + 3, last)];
        float xn0 = __half2float(h1[(size_t)sp0 * 64 + lane]);
        float an0 = ald[sp0 * 8 + head];
        float xn1 = __half2float(h1[(size_t)sp1 * 64 + lane]);
        float an1 = ald[sp1 * 8 + head];

        float dot0 = xi * xj0, dot1 = xi * xj1;
        dot0 += __shfl_xor(dot0, 1); dot1 += __shfl_xor(dot1, 1);
        dot0 += __shfl_xor(dot0, 2); dot1 += __shfl_xor(dot1, 2);
        dot0 += __shfl_xor(dot0, 4); dot1 += __shfl_xor(dot1, 4);
        float sig0 = __builtin_amdgcn_rcpf(1.f + __builtin_amdgcn_exp2f(dot0 * -LOG2E));
        float sig1 = __builtin_amdgcn_rcpf(1.f + __builtin_amdgcn_exp2f(dot1 * -LOG2E));
        float g0 = (aj0 + ardi) * sig0;
        float g1 = (aj1 + ardi) * sig1;
        float a20 = fmaxf(g0, NEG_SLOPE * g0);
        float a21 = (e + 1 < end) ? fmaxf(g1, NEG_SLOPE * g1) : -INFINITY;
        float pm = fmaxf(a20, a21);
        if (__any(pm > m2 + 11.5f)) {
            float mn = fmaxf(m2, pm);
            float so = __builtin_amdgcn_exp2f(m2 - mn);
            lsum *= so; accv *= so; m2 = mn;
        }
        float p0 = __builtin_amdgcn_exp2f(a20 - m2);
        float p1 = __builtin_amdgcn_exp2f(a21 - m2);
        lsum += p0 + p1;
        accv += p0 * xj0 + p1 * xj1;
        xj0 = xn0; aj0 = an0; xj1 = xn1; aj1 = an1;
    }
    float o = accv * __builtin_amdgcn_rcpf(lsum) + b1[lane];
    o = o > 0.f ? o : (__builtin_amdgcn_exp2f(o * LOG2E) - 1.f);  // ELU
    hout[(size_t)wid * 64 + lane] = o;
}

// ---------------- GEMM2: h2 = hout @ W2  (N x 64) @ (64 x 128), h2 stored fp16x2 ------
// + fused per-node att dots for layer 2.
__global__ __launch_bounds__(256) void gemm2_k(const float* __restrict__ h,
                                               const float* __restrict__ W2,
                                               const float* __restrict__ attl,
                                               const float* __restrict__ attr,
                                               __half2* __restrict__ h2,
                                               float* __restrict__ ald,
                                               float* __restrict__ ard) {
    __shared__ float xs[32 * 64];
    int t = threadIdx.x;
    int row0 = blockIdx.x * 32;
    for (int i = t; i < 32 * 16; i += 256) {
        int r = i >> 4, q = i & 15;
        int gr = row0 + r;
        float4 v = make_float4(0.f, 0.f, 0.f, 0.f);
        if (gr < N_NODES) v = ((const float4*)h)[(size_t)gr * 16 + q];
        ((float4*)xs)[r * 16 + q] = v;
    }
    __syncthreads();
    int w = t >> 6, lane = t & 63;
    int r0 = w * 8;
    float2 acc[8];
#pragma unroll
    for (int r = 0; r < 8; ++r) acc[r] = make_float2(0.f, 0.f);
    for (int k = 0; k < 64; ++k) {
        float2 wv = ((const float2*)W2)[k * 64 + lane];
#pragma unroll
        for (int r = 0; r < 8; ++r) {
            float xv = xs[(r0 + r) * 64 + k];
            acc[r].x += xv * wv.x;
            acc[r].y += xv * wv.y;
        }
    }
    float2 al = ((const float2*)attl)[lane];
    float2 ar = ((const float2*)attr)[lane];
#pragma unroll
    for (int r = 0; r < 8; ++r) {
        int gr = row0 + r0 + r;
        float vl = acc[r].x * al.x + acc[r].y * al.y;
        float vr = acc[r].x * ar.x + acc[r].y * ar.y;
        vl += __shfl_xor(vl, 1); vr += __shfl_xor(vr, 1);
        vl += __shfl_xor(vl, 2); vr += __shfl_xor(vr, 2);
        vl += __shfl_xor(vl, 4); vr += __shfl_xor(vr, 4);
        if (gr < N_NODES) {
            h2[(size_t)gr * 64 + lane] = __floats2half2_rn(acc[r].x, acc[r].y);
            if ((lane & 7) == 0) {
                ald[gr * 8 + (lane >> 3)] = vl * LOG2E;
                ard[gr * 8 + (lane >> 3)] = vr * LOG2E;
            }
        }
    }
}

// ---------------- attn2: one wave per node, 2 ch/lane (fp16x2 gathers) ----------------
// online softmax (exp2, defer-max), 2-edge pipeline + head mean + bias + log_softmax
__global__ __launch_bounds__(256) void attn2_k(const __half2* __restrict__ h2,
                                               const int* __restrict__ rowptr,
                                               const int* __restrict__ col,
                                               const float* __restrict__ ald,
                                               const float* __restrict__ ard,
                                               const float* __restrict__ b2,
                                               float* __restrict__ out) {
    int wid = (blockIdx.x * blockDim.x + threadIdx.x) >> 6;  // node
    int lane = threadIdx.x & 63;
    if (wid >= N_NODES) return;
    int head = lane >> 3;
    float2 xi = __half22float2(h2[(size_t)wid * 64 + lane]);
    float ardi = ard[wid * 8 + head];
    int beg = rowptr[wid], end = rowptr[wid + 1];
    int last = end - 1;

    int s0 = col[beg];
    int s1 = col[min(beg + 1, last)];
    float2 xj0 = __half22float2(h2[(size_t)s0 * 64 + lane]);
    float aj0 = ald[s0 * 8 + head];
    float2 xj1 = __half22float2(h2[(size_t)s1 * 64 + lane]);
    float aj1 = ald[s1 * 8 + head];

    float m2 = -INFINITY, lsum = 0.f;
    float2 acc = make_float2(0.f, 0.f);
    for (int e = beg; e < end; e += 2) {
        int sp0 = col[min(e + 2, last)];
        int sp1 = col[min(e + 3, last)];
        float2 xn0 = __half22float2(h2[(size_t)sp0 * 64 + lane]);
        float an0 = ald[sp0 * 8 + head];
        float2 xn1 = __half22float2(h2[(size_t)sp1 * 64 + lane]);
        float an1 = ald[sp1 * 8 + head];

        float dot0 = xi.x * xj0.x + xi.y * xj0.y;
        float dot1 = xi.x * xj1.x + xi.y * xj1.y;
        dot0 += __shfl_xor(dot0, 1); dot1 += __shfl_xor(dot1, 1);
        dot0 += __shfl_xor(dot0, 2); dot1 += __shfl_xor(dot1, 2);
        dot0 += __shfl_xor(dot0, 4); dot1 += __shfl_xor(dot1, 4);
        float sig0 = __builtin_amdgcn_rcpf(1.f + __builtin_amdgcn_exp2f(dot0 * -LOG2E));
        float sig1 = __builtin_amdgcn_rcpf(1.f + __builtin_amdgcn_exp2f(dot1 * -LOG2E));
        float g0 = (aj0 + ardi) * sig0;
        float g1 = (aj1 + ardi) * sig1;
        float a20 = fmaxf(g0, NEG_SLOPE * g0);
        float a21 = (e + 1 < end) ? fmaxf(g1, NEG_SLOPE * g1) : -INFINITY;
        float pm = fmaxf(a20, a21);
        if (__any(pm > m2 + 11.5f)) {
            float mn = fmaxf(m2, pm);
            float so = __builtin_amdgcn_exp2f(m2 - mn);
            lsum *= so; acc.x *= so; acc.y *= so; m2 = mn;
        }
        float p0 = __builtin_amdgcn_exp2f(a20 - m2);
        float p1 = __builtin_amdgcn_exp2f(a21 - m2);
        lsum += p0 + p1;
        acc.x += p0 * xj0.x + p1 * xj1.x;
        acc.y += p0 * xj0.y + p1 * xj1.y;
        xj0 = xn0; aj0 = an0; xj1 = xn1; aj1 = an1;
    }
    float rl = __builtin_amdgcn_rcpf(lsum);
    float ox = acc.x * rl;
    float oy = acc.y * rl;
    // mean over heads: lanes with equal (l&7) hold same channel pair across heads
    ox += __shfl_xor(ox, 8); oy += __shfl_xor(oy, 8);
    ox += __shfl_xor(ox, 16); oy += __shfl_xor(oy, 16);
    ox += __shfl_xor(ox, 32); oy += __shfl_xor(oy, 32);
    int c2 = (lane & 7) * 2;
    float vx = ox * 0.125f + b2[c2];
    float vy = oy * 0.125f + b2[c2 + 1];
    // log_softmax across 16 channels held by the 8-lane group (2 per lane)
    float mx = fmaxf(vx, vy);
    mx = fmaxf(mx, __shfl_xor(mx, 1));
    mx = fmaxf(mx, __shfl_xor(mx, 2));
    mx = fmaxf(mx, __shfl_xor(mx, 4));
    float se = __expf(vx - mx) + __expf(vy - mx);
    se += __shfl_xor(se, 1); se += __shfl_xor(se, 2); se += __shfl_xor(se, 4);
    float ls = __logf(se);
    if (lane < 8)
        ((float2*)out)[(size_t)wid * 8 + lane] = make_float2(vx - mx - ls, vy - mx - ls);
}

// ---------------- host ----------------
extern "C" void kernel_launch(void* const* d_in, const int* in_sizes, int n_in,
                              void* d_out, int out_size, void* d_ws, size_t ws_size,
                              hipStream_t stream) {
    const float* x     = (const float*)d_in[0];
    const int*   ei    = (const int*)d_in[1];
    const float* W1    = (const float*)d_in[2];
    const float* attl1 = (const float*)d_in[3];
    const float* attr1 = (const float*)d_in[4];
    const float* b1    = (const float*)d_in[5];
    const float* W2    = (const float*)d_in[6];
    const float* attl2 = (const float*)d_in[7];
    const float* attr2 = (const float*)d_in[8];
    const float* b2    = (const float*)d_in[9];
    float* out = (float*)d_out;

    char* ws = (char*)d_ws;
    size_t off = 0;
    auto alloc = [&](size_t bytes) {
        size_t o = off;
        off += (bytes + 255) & ~(size_t)255;
        return o;
    };
    size_t o_flag   = alloc(4);
    size_t o_counts = alloc((size_t)N_NODES * 4);
    size_t o_fill   = alloc((size_t)N_NODES * 4);
    size_t o_rowptr = alloc((size_t)(N_NODES + 1) * 4);
    size_t o_bsums  = alloc(1024 * 4);
    size_t o_col    = alloc((size_t)EPRIME * 4);
    size_t o_h1     = alloc((size_t)N_NODES * 64 * 4);   // (over-alloc; h1 is fp16)
    size_t o_hout   = alloc((size_t)N_NODES * 64 * 4);
    size_t o_h2     = alloc((size_t)N_NODES * 128 * 4);  // (over-alloc; h2 is fp16)
    size_t o_w1f    = alloc((size_t)512 * 64 * 2);       // fp16 swizzled W1

    size_t aldsz = ((size_t)N_NODES * 8 * 4 + 255) & ~(size_t)255;
    // layer-1 att dots alias the h2 region (h2 written later, after attn1 reads these)
    size_t o_ald1 = o_h2;
    size_t o_ard1 = o_h2 + aldsz;
    // layer-2 att dots alias the h1 region (h1 dead after attn1)
    size_t o_ald2 = o_h1;
    size_t o_ard2 = o_h1 + aldsz;

    unsigned* flag = (unsigned*)(ws + o_flag);
    int* counts = (int*)(ws + o_counts);
    int* fill   = (int*)(ws + o_fill);
    int* rowptr = (int*)(ws + o_rowptr);
    int* bsums  = (int*)(ws + o_bsums);
    int* col    = (int*)(ws + o_col);
    __half* h1  = (__half*)(ws + o_h1);
    float* hout = (float*)(ws + o_hout);
    __half2* h2 = (__half2*)(ws + o_h2);
    _Float16* w1f = (_Float16*)(ws + o_w1f);
    float* ald1 = (float*)(ws + o_ald1);
    float* ard1 = (float*)(ws + o_ard1);
    float* ald2 = (float*)(ws + o_ald2);
    float* ard2 = (float*)(ws + o_ard2);

    int nscan = (N_NODES + 1 + 1023) / 1024;  // 99

    hipLaunchKernelGGL(detect_k, dim3(1), dim3(256), 0, stream, (const unsigned*)ei, flag);
    hipLaunchKernelGGL(init_k, dim3((N_NODES + 255) / 256), dim3(256), 0, stream, counts, fill);
    hipLaunchKernelGGL(count_k, dim3((N_EDGES + 255) / 256), dim3(256), 0, stream, ei, flag, counts);
    hipLaunchKernelGGL(scan1_k, dim3(nscan), dim3(256), 0, stream, counts, rowptr, bsums);
    hipLaunchKernelGGL(scan2_k, dim3(1), dim3(64), 0, stream, bsums, nscan);
    hipLaunchKernelGGL(scan3_k, dim3(nscan), dim3(256), 0, stream, rowptr, bsums);
    hipLaunchKernelGGL(scatter_k, dim3((EPRIME + 255) / 256), dim3(256), 0, stream,
                       ei, flag, rowptr, fill, col);
    hipLaunchKernelGGL(w1cvt_k, dim3(128), dim3(256), 0, stream, W1, w1f);
    hipLaunchKernelGGL(gemm1_k, dim3((N_NODES + 63) / 64), dim3(256), 0, stream,
                       x, w1f, attl1, attr1, h1, ald1, ard1);
    hipLaunchKernelGGL(attn1_k, dim3((N_NODES + 3) / 4), dim3(256), 0, stream,
                       h1, rowptr, col, ald1, ard1, b1, hout);
    hipLaunchKernelGGL(gemm2_k, dim3((N_NODES + 31) / 32), dim3(256), 0, stream,
                       hout, W2, attl2, attr2, h2, ald2, ard2);
    hipLaunchKernelGGL(attn2_k, dim3((N_NODES + 3) / 4), dim3(256), 0, stream,
                       h2, rowptr, col, ald2, ard2, b2, out);
}

// Round 11
// 488.664 us; speedup vs baseline: 1.5800x; 1.0815x over previous
//
#include <hip/hip_runtime.h>
#include <hip/hip_fp16.h>
#include <math.h>

#define N_NODES 100000
#define N_EDGES 1600000
#define EPRIME  (N_EDGES + N_NODES)
#define NEG_SLOPE 0.2f
#define LOG2E 1.44269504f

typedef _Float16 f16x8 __attribute__((ext_vector_type(8)));
typedef float f32x4 __attribute__((ext_vector_type(4)));

// ---------------- edge dtype detect (int64 vs int32) ----------------
__global__ __launch_bounds__(256) void detect_k(const unsigned* __restrict__ w,
                                                unsigned* __restrict__ flag) {
    __shared__ int any;
    if (threadIdx.x == 0) any = 0;
    __syncthreads();
    int nz = 0;
    for (int i = threadIdx.x; i < 1024; i += 256)
        if (w[2 * i + 1] != 0u) nz = 1;
    if (nz) atomicOr(&any, 1);
    __syncthreads();
    if (threadIdx.x == 0) flag[0] = any ? 0u : 1u;  // 1 => int64
}

// ---------------- CSR build ----------------
__global__ __launch_bounds__(256) void init_k(int* __restrict__ counts,
                                              int* __restrict__ fill) {
    int n = blockIdx.x * blockDim.x + threadIdx.x;
    if (n < N_NODES) { counts[n] = 1; fill[n] = 0; }  // 1 = self loop
}

__global__ __launch_bounds__(256) void count_k(const int* __restrict__ ei,
                                               const unsigned* __restrict__ flag,
                                               int* __restrict__ counts) {
    int e = blockIdx.x * blockDim.x + threadIdx.x;
    if (e >= N_EDGES) return;
    int d = flag[0] ? ei[2 * (N_EDGES + e)] : ei[N_EDGES + e];
    atomicAdd(&counts[d], 1);
}

// exclusive scan of counts[0..N-1] -> rowptr[0..N], 1024 elems/block
__global__ __launch_bounds__(256) void scan1_k(const int* __restrict__ counts,
                                               int* __restrict__ rowptr,
                                               int* __restrict__ bsums) {
    __shared__ int s[256];
    int t = threadIdx.x;
    int base = blockIdx.x * 1024 + t * 4;
    int v[4];
#pragma unroll
    for (int j = 0; j < 4; ++j)
        v[j] = (base + j < N_NODES) ? counts[base + j] : 0;
    int tsum = v[0] + v[1] + v[2] + v[3];
    s[t] = tsum;
    __syncthreads();
    for (int off = 1; off < 256; off <<= 1) {
        int x = (t >= off) ? s[t - off] : 0;
        __syncthreads();
        s[t] += x;
        __syncthreads();
    }
    if (t == 255) bsums[blockIdx.x] = s[255];
    int run = s[t] - tsum;  // exclusive prefix for this thread (block-local)
#pragma unroll
    for (int j = 0; j < 4; ++j) {
        if (base + j <= N_NODES) rowptr[base + j] = run;
        run += v[j];
    }
}

__global__ void scan2_k(int* __restrict__ bsums, int nb) {
    if (threadIdx.x == 0 && blockIdx.x == 0) {
        int run = 0;
        for (int i = 0; i < nb; ++i) { int c = bsums[i]; bsums[i] = run; run += c; }
    }
}

__global__ __launch_bounds__(256) void scan3_k(int* __restrict__ rowptr,
                                               const int* __restrict__ bsums) {
    int t = threadIdx.x;
    int base = blockIdx.x * 1024 + t * 4;
    int add = bsums[blockIdx.x];
#pragma unroll
    for (int j = 0; j < 4; ++j)
        if (base + j <= N_NODES) rowptr[base + j] += add;
}

__global__ __launch_bounds__(256) void scatter_k(const int* __restrict__ ei,
                                                 const unsigned* __restrict__ flag,
                                                 const int* __restrict__ rowptr,
                                                 int* __restrict__ fill,
                                                 int* __restrict__ col) {
    int t = blockIdx.x * blockDim.x + threadIdx.x;
    if (t < 8) col[EPRIME + t] = 0;  // sentinel pad: lets attn loops skip min() clamps
    if (t >= EPRIME) return;
    int s, d;
    if (t < N_EDGES) {
        if (flag[0]) { s = ei[2 * t]; d = ei[2 * (N_EDGES + t)]; }
        else         { s = ei[t];     d = ei[N_EDGES + t]; }
    } else {
        s = d = t - N_EDGES;
    }
    int pos = rowptr[d] + atomicAdd(&fill[d], 1);
    col[pos] = s;
}

// ---------------- W1 -> fp16 fragment-order pre-swizzle ----------------
// Slot idx = ((ks*4 + nt)*64 + lane)*8 + j  holds  W1[k][c] with
// k = ks*32 + 8*(lane>>4) + j,  c = nt*16 + (lane&15).
__global__ __launch_bounds__(256) void w1cvt_k(const float* __restrict__ W1,
                                               _Float16* __restrict__ W1f) {
    int idx = blockIdx.x * 256 + threadIdx.x;
    if (idx >= 512 * 64) return;
    int j    = idx & 7;
    int lane = (idx >> 3) & 63;
    int nt   = (idx >> 9) & 3;
    int ks   = idx >> 11;
    int k = ks * 32 + (lane >> 4) * 8 + j;
    int c = nt * 16 + (lane & 15);
    W1f[idx] = (_Float16)W1[k * 64 + c];
}

// ---------------- GEMM1 (MFMA): h1 = x @ W1, h1 fp16 + fused att dots --------
// v7 (R9, verified): mfma_f32_16x16x32_f16, wave = 16 rows x 64 cols, no LDS,
// no barriers. D layout (m89): row=(lane>>4)*4+reg, col=lane&15.
__global__ __launch_bounds__(256) void gemm1_k(const float* __restrict__ x,
                                               const _Float16* __restrict__ W1f,
                                               const float* __restrict__ attl,
                                               const float* __restrict__ attr,
                                               __half* __restrict__ h1,
                                               float* __restrict__ ald,
                                               float* __restrict__ ard) {
    int t = threadIdx.x;
    int w = t >> 6, l = t & 63;
    int rw0 = blockIdx.x * 64 + w * 16;
    int arow = rw0 + (l & 15);
    if (arow >= N_NODES) arow = N_NODES - 1;  // clamp; OOB outputs are guarded
    int kg = l >> 4;                           // k-group 0..3
    const float4* x4 = (const float4*)(x + (size_t)arow * 512);
    const f16x8* w8 = (const f16x8*)W1f;

    f32x4 acc0 = {0.f, 0.f, 0.f, 0.f};
    f32x4 acc1 = {0.f, 0.f, 0.f, 0.f};
    f32x4 acc2 = {0.f, 0.f, 0.f, 0.f};
    f32x4 acc3 = {0.f, 0.f, 0.f, 0.f};

#pragma unroll 4
    for (int ks = 0; ks < 16; ++ks) {
        float4 a0 = x4[ks * 8 + kg * 2];
        float4 a1 = x4[ks * 8 + kg * 2 + 1];
        f16x8 af;
        af[0] = (_Float16)a0.x; af[1] = (_Float16)a0.y;
        af[2] = (_Float16)a0.z; af[3] = (_Float16)a0.w;
        af[4] = (_Float16)a1.x; af[5] = (_Float16)a1.y;
        af[6] = (_Float16)a1.z; af[7] = (_Float16)a1.w;
        f16x8 b0 = w8[(ks * 4 + 0) * 64 + l];
        f16x8 b1 = w8[(ks * 4 + 1) * 64 + l];
        f16x8 b2 = w8[(ks * 4 + 2) * 64 + l];
        f16x8 b3 = w8[(ks * 4 + 3) * 64 + l];
        acc0 = __builtin_amdgcn_mfma_f32_16x16x32_f16(af, b0, acc0, 0, 0, 0);
        acc1 = __builtin_amdgcn_mfma_f32_16x16x32_f16(af, b1, acc1, 0, 0, 0);
        acc2 = __builtin_amdgcn_mfma_f32_16x16x32_f16(af, b2, acc2, 0, 0, 0);
        acc3 = __builtin_amdgcn_mfma_f32_16x16x32_f16(af, b3, acc3, 0, 0, 0);
    }

    // epilogue: lane holds D rows rw0+(l>>4)*4+reg, cols nt*16+(l&15)
    int col = l & 15;
    int hi = col >> 3;  // head parity within a 16-col tile
    float al0 = attl[col], al1 = attl[16 + col], al2 = attl[32 + col], al3 = attl[48 + col];
    float ar0 = attr[col], ar1 = attr[16 + col], ar2 = attr[32 + col], ar3 = attr[48 + col];

#pragma unroll
    for (int reg = 0; reg < 4; ++reg) {
        int grow = rw0 + (l >> 4) * 4 + reg;
        bool v = grow < N_NODES;
        float c0 = acc0[reg], c1 = acc1[reg], c2 = acc2[reg], c3 = acc3[reg];
        if (v) {
            __half* hp = h1 + (size_t)grow * 64;
            hp[col]      = __float2half_rn(c0);
            hp[16 + col] = __float2half_rn(c1);
            hp[32 + col] = __float2half_rn(c2);
            hp[48 + col] = __float2half_rn(c3);
        }
        // att dots: head = nt*2 + hi; 8 lanes (xor 1,2,4) hold that head's cols
        float vl0 = c0 * al0, vl1 = c1 * al1, vl2 = c2 * al2, vl3 = c3 * al3;
        float vr0 = c0 * ar0, vr1 = c1 * ar1, vr2 = c2 * ar2, vr3 = c3 * ar3;
        vl0 += __shfl_xor(vl0, 1); vl1 += __shfl_xor(vl1, 1);
        vl2 += __shfl_xor(vl2, 1); vl3 += __shfl_xor(vl3, 1);
        vr0 += __shfl_xor(vr0, 1); vr1 += __shfl_xor(vr1, 1);
        vr2 += __shfl_xor(vr2, 1); vr3 += __shfl_xor(vr3, 1);
        vl0 += __shfl_xor(vl0, 2); vl1 += __shfl_xor(vl1, 2);
        vl2 += __shfl_xor(vl2, 2); vl3 += __shfl_xor(vl3, 2);
        vr0 += __shfl_xor(vr0, 2); vr1 += __shfl_xor(vr1, 2);
        vr2 += __shfl_xor(vr2, 2); vr3 += __shfl_xor(vr3, 2);
        vl0 += __shfl_xor(vl0, 4); vl1 += __shfl_xor(vl1, 4);
        vl2 += __shfl_xor(vl2, 4); vl3 += __shfl_xor(vl3, 4);
        vr0 += __shfl_xor(vr0, 4); vr1 += __shfl_xor(vr1, 4);
        vr2 += __shfl_xor(vr2, 4); vr3 += __shfl_xor(vr3, 4);
        if (v && (l & 7) == 0) {
            float* alp = ald + (size_t)grow * 8;
            float* arp = ard + (size_t)grow * 8;
            alp[0 + hi] = vl0 * LOG2E; alp[2 + hi] = vl1 * LOG2E;
            alp[4 + hi] = vl2 * LOG2E; alp[6 + hi] = vl3 * LOG2E;
            arp[0 + hi] = vr0 * LOG2E; arp[2 + hi] = vr1 * LOG2E;
            arp[4 + hi] = vr2 * LOG2E; arp[6 + hi] = vr3 * LOG2E;
        }
    }
}

// ---------------- attn1: wave per node, lane = channel (64ch, fp16 gathers) ----------
// v2: VALU-cut — 32-bit byte-offset gathers (saddr form), sentinel-padded col
// (no min clamps), 4-edge unrolled pipeline (amortized __any + loop overhead).
__global__ __launch_bounds__(256) void attn1_k(const __half* __restrict__ h1,
                                               const int* __restrict__ rowptr,
                                               const int* __restrict__ col,
                                               const float* __restrict__ ald,
                                               const float* __restrict__ ard,
                                               const float* __restrict__ b1,
                                               float* __restrict__ hout) {
    int wid = (blockIdx.x * blockDim.x + threadIdx.x) >> 6;  // node
    int lane = threadIdx.x & 63;
    if (wid >= N_NODES) return;
    int head = lane >> 3;
    const char* hb = (const char*)h1;
    const char* ab = (const char*)ald;
    unsigned loff = (unsigned)lane * 2u;
    unsigned hoff = (unsigned)head * 4u;
    float xi = __half2float(*(const __half*)(hb + (unsigned)wid * 128u + loff));
    float ardi = ard[wid * 8 + head];
    int beg = rowptr[wid], end = rowptr[wid + 1];

    int s0 = col[beg], s1 = col[beg + 1], s2 = col[beg + 2], s3 = col[beg + 3];
    float xj0 = __half2float(*(const __half*)(hb + (unsigned)s0 * 128u + loff));
    float aj0 = *(const float*)(ab + (unsigned)s0 * 32u + hoff);
    float xj1 = __half2float(*(const __half*)(hb + (unsigned)s1 * 128u + loff));
    float aj1 = *(const float*)(ab + (unsigned)s1 * 32u + hoff);
    float xj2 = __half2float(*(const __half*)(hb + (unsigned)s2 * 128u + loff));
    float aj2 = *(const float*)(ab + (unsigned)s2 * 32u + hoff);
    float xj3 = __half2float(*(const __half*)(hb + (unsigned)s3 * 128u + loff));
    float aj3 = *(const float*)(ab + (unsigned)s3 * 32u + hoff);

    float m2 = -INFINITY, lsum = 0.f, accv = 0.f;
    for (int e = beg; e < end; e += 4) {
        int t0 = col[e + 4], t1 = col[e + 5], t2 = col[e + 6], t3 = col[e + 7];
        float y0 = __half2float(*(const __half*)(hb + (unsigned)t0 * 128u + loff));
        float c0 = *(const float*)(ab + (unsigned)t0 * 32u + hoff);
        float y1 = __half2float(*(const __half*)(hb + (unsigned)t1 * 128u + loff));
        float c1 = *(const float*)(ab + (unsigned)t1 * 32u + hoff);
        float y2 = __half2float(*(const __half*)(hb + (unsigned)t2 * 128u + loff));
        float c2 = *(const float*)(ab + (unsigned)t2 * 32u + hoff);
        float y3 = __half2float(*(const __half*)(hb + (unsigned)t3 * 128u + loff));
        float c3 = *(const float*)(ab + (unsigned)t3 * 32u + hoff);

        float d0 = xi * xj0, d1 = xi * xj1, d2 = xi * xj2, d3 = xi * xj3;
        d0 += __shfl_xor(d0, 1); d1 += __shfl_xor(d1, 1);
        d2 += __shfl_xor(d2, 1); d3 += __shfl_xor(d3, 1);
        d0 += __shfl_xor(d0, 2); d1 += __shfl_xor(d1, 2);
        d2 += __shfl_xor(d2, 2); d3 += __shfl_xor(d3, 2);
        d0 += __shfl_xor(d0, 4); d1 += __shfl_xor(d1, 4);
        d2 += __shfl_xor(d2, 4); d3 += __shfl_xor(d3, 4);
        float g0 = (aj0 + ardi) * __builtin_amdgcn_rcpf(1.f + __builtin_amdgcn_exp2f(d0 * -LOG2E));
        float g1 = (aj1 + ardi) * __builtin_amdgcn_rcpf(1.f + __builtin_amdgcn_exp2f(d1 * -LOG2E));
        float g2 = (aj2 + ardi) * __builtin_amdgcn_rcpf(1.f + __builtin_amdgcn_exp2f(d2 * -LOG2E));
        float g3 = (aj3 + ardi) * __builtin_amdgcn_rcpf(1.f + __builtin_amdgcn_exp2f(d3 * -LOG2E));
        float a0 = fmaxf(g0, NEG_SLOPE * g0);
        float a1 = (e + 1 < end) ? fmaxf(g1, NEG_SLOPE * g1) : -INFINITY;
        float a2 = (e + 2 < end) ? fmaxf(g2, NEG_SLOPE * g2) : -INFINITY;
        float a3 = (e + 3 < end) ? fmaxf(g3, NEG_SLOPE * g3) : -INFINITY;
        float pm = fmaxf(fmaxf(a0, a1), fmaxf(a2, a3));
        if (__any(pm > m2 + 11.5f)) {
            float mn = fmaxf(m2, pm);
            float so = __builtin_amdgcn_exp2f(m2 - mn);
            lsum *= so; accv *= so; m2 = mn;
        }
        float p0 = __builtin_amdgcn_exp2f(a0 - m2);
        float p1 = __builtin_amdgcn_exp2f(a1 - m2);
        float p2 = __builtin_amdgcn_exp2f(a2 - m2);
        float p3 = __builtin_amdgcn_exp2f(a3 - m2);
        lsum += (p0 + p1) + (p2 + p3);
        accv += p0 * xj0 + p1 * xj1 + p2 * xj2 + p3 * xj3;
        xj0 = y0; aj0 = c0; xj1 = y1; aj1 = c1;
        xj2 = y2; aj2 = c2; xj3 = y3; aj3 = c3;
    }
    float o = accv * __builtin_amdgcn_rcpf(lsum) + b1[lane];
    o = o > 0.f ? o : (__builtin_amdgcn_exp2f(o * LOG2E) - 1.f);  // ELU
    hout[(size_t)wid * 64 + lane] = o;
}

// ---------------- GEMM2: h2 = hout @ W2  (N x 64) @ (64 x 128), h2 stored fp16x2 ------
// + fused per-node att dots for layer 2.
__global__ __launch_bounds__(256) void gemm2_k(const float* __restrict__ h,
                                               const float* __restrict__ W2,
                                               const float* __restrict__ attl,
                                               const float* __restrict__ attr,
                                               __half2* __restrict__ h2,
                                               float* __restrict__ ald,
                                               float* __restrict__ ard) {
    __shared__ float xs[32 * 64];
    int t = threadIdx.x;
    int row0 = blockIdx.x * 32;
    for (int i = t; i < 32 * 16; i += 256) {
        int r = i >> 4, q = i & 15;
        int gr = row0 + r;
        float4 v = make_float4(0.f, 0.f, 0.f, 0.f);
        if (gr < N_NODES) v = ((const float4*)h)[(size_t)gr * 16 + q];
        ((float4*)xs)[r * 16 + q] = v;
    }
    __syncthreads();
    int w = t >> 6, lane = t & 63;
    int r0 = w * 8;
    float2 acc[8];
#pragma unroll
    for (int r = 0; r < 8; ++r) acc[r] = make_float2(0.f, 0.f);
    for (int k = 0; k < 64; ++k) {
        float2 wv = ((const float2*)W2)[k * 64 + lane];
#pragma unroll
        for (int r = 0; r < 8; ++r) {
            float xv = xs[(r0 + r) * 64 + k];
            acc[r].x += xv * wv.x;
            acc[r].y += xv * wv.y;
        }
    }
    float2 al = ((const float2*)attl)[lane];
    float2 ar = ((const float2*)attr)[lane];
#pragma unroll
    for (int r = 0; r < 8; ++r) {
        int gr = row0 + r0 + r;
        float vl = acc[r].x * al.x + acc[r].y * al.y;
        float vr = acc[r].x * ar.x + acc[r].y * ar.y;
        vl += __shfl_xor(vl, 1); vr += __shfl_xor(vr, 1);
        vl += __shfl_xor(vl, 2); vr += __shfl_xor(vr, 2);
        vl += __shfl_xor(vl, 4); vr += __shfl_xor(vr, 4);
        if (gr < N_NODES) {
            h2[(size_t)gr * 64 + lane] = __floats2half2_rn(acc[r].x, acc[r].y);
            if ((lane & 7) == 0) {
                ald[gr * 8 + (lane >> 3)] = vl * LOG2E;
                ard[gr * 8 + (lane >> 3)] = vr * LOG2E;
            }
        }
    }
}

// ---------------- attn2: wave per node, 2 ch/lane (fp16x2 gathers) --------------------
// v2: same VALU-cut as attn1 (32-bit offsets, padded col, 4-edge pipeline)
// + head mean + bias + log_softmax epilogue.
__global__ __launch_bounds__(256) void attn2_k(const __half2* __restrict__ h2,
                                               const int* __restrict__ rowptr,
                                               const int* __restrict__ col,
                                               const float* __restrict__ ald,
                                               const float* __restrict__ ard,
                                               const float* __restrict__ b2,
                                               float* __restrict__ out) {
    int wid = (blockIdx.x * blockDim.x + threadIdx.x) >> 6;  // node
    int lane = threadIdx.x & 63;
    if (wid >= N_NODES) return;
    int head = lane >> 3;
    const char* hb = (const char*)h2;
    const char* ab = (const char*)ald;
    unsigned loff = (unsigned)lane * 4u;
    unsigned hoff = (unsigned)head * 4u;
    float2 xi = __half22float2(*(const __half2*)(hb + (unsigned)wid * 256u + loff));
    float ardi = ard[wid * 8 + head];
    int beg = rowptr[wid], end = rowptr[wid + 1];

    int s0 = col[beg], s1 = col[beg + 1], s2 = col[beg + 2], s3 = col[beg + 3];
    float2 xj0 = __half22float2(*(const __half2*)(hb + (unsigned)s0 * 256u + loff));
    float aj0 = *(const float*)(ab + (unsigned)s0 * 32u + hoff);
    float2 xj1 = __half22float2(*(const __half2*)(hb + (unsigned)s1 * 256u + loff));
    float aj1 = *(const float*)(ab + (unsigned)s1 * 32u + hoff);
    float2 xj2 = __half22float2(*(const __half2*)(hb + (unsigned)s2 * 256u + loff));
    float aj2 = *(const float*)(ab + (unsigned)s2 * 32u + hoff);
    float2 xj3 = __half22float2(*(const __half2*)(hb + (unsigned)s3 * 256u + loff));
    float aj3 = *(const float*)(ab + (unsigned)s3 * 32u + hoff);

    float m2 = -INFINITY, lsum = 0.f;
    float2 acc = make_float2(0.f, 0.f);
    for (int e = beg; e < end; e += 4) {
        int t0 = col[e + 4], t1 = col[e + 5], t2 = col[e + 6], t3 = col[e + 7];
        float2 y0 = __half22float2(*(const __half2*)(hb + (unsigned)t0 * 256u + loff));
        float c0 = *(const float*)(ab + (unsigned)t0 * 32u + hoff);
        float2 y1 = __half22float2(*(const __half2*)(hb + (unsigned)t1 * 256u + loff));
        float c1 = *(const float*)(ab + (unsigned)t1 * 32u + hoff);
        float2 y2 = __half22float2(*(const __half2*)(hb + (unsigned)t2 * 256u + loff));
        float c2 = *(const float*)(ab + (unsigned)t2 * 32u + hoff);
        float2 y3 = __half22float2(*(const __half2*)(hb + (unsigned)t3 * 256u + loff));
        float c3 = *(const float*)(ab + (unsigned)t3 * 32u + hoff);

        float d0 = xi.x * xj0.x + xi.y * xj0.y;
        float d1 = xi.x * xj1.x + xi.y * xj1.y;
        float d2 = xi.x * xj2.x + xi.y * xj2.y;
        float d3 = xi.x * xj3.x + xi.y * xj3.y;
        d0 += __shfl_xor(d0, 1); d1 += __shfl_xor(d1, 1);
        d2 += __shfl_xor(d2, 1); d3 += __shfl_xor(d3, 1);
        d0 += __shfl_xor(d0, 2); d1 += __shfl_xor(d1, 2);
        d2 += __shfl_xor(d2, 2); d3 += __shfl_xor(d3, 2);
        d0 += __shfl_xor(d0, 4); d1 += __shfl_xor(d1, 4);
        d2 += __shfl_xor(d2, 4); d3 += __shfl_xor(d3, 4);
        float g0 = (aj0 + ardi) * __builtin_amdgcn_rcpf(1.f + __builtin_amdgcn_exp2f(d0 * -LOG2E));
        float g1 = (aj1 + ardi) * __builtin_amdgcn_rcpf(1.f + __builtin_amdgcn_exp2f(d1 * -LOG2E));
        float g2 = (aj2 + ardi) * __builtin_amdgcn_rcpf(1.f + __builtin_amdgcn_exp2f(d2 * -LOG2E));
        float g3 = (aj3 + ardi) * __builtin_amdgcn_rcpf(1.f + __builtin_amdgcn_exp2f(d3 * -LOG2E));
        float a0 = fmaxf(g0, NEG_SLOPE * g0);
        float a1 = (e + 1 < end) ? fmaxf(g1, NEG_SLOPE * g1) : -INFINITY;
        float a2 = (e + 2 < end) ? fmaxf(g2, NEG_SLOPE * g2) : -INFINITY;
        float a3 = (e + 3 < end) ? fmaxf(g3, NEG_SLOPE * g3) : -INFINITY;
        float pm = fmaxf(fmaxf(a0, a1), fmaxf(a2, a3));
        if (__any(pm > m2 + 11.5f)) {
            float mn = fmaxf(m2, pm);
            float so = __builtin_amdgcn_exp2f(m2 - mn);
            lsum *= so; acc.x *= so; acc.y *= so; m2 = mn;
        }
        float p0 = __builtin_amdgcn_exp2f(a0 - m2);
        float p1 = __builtin_amdgcn_exp2f(a1 - m2);
        float p2 = __builtin_amdgcn_exp2f(a2 - m2);
        float p3 = __builtin_amdgcn_exp2f(a3 - m2);
        lsum += (p0 + p1) + (p2 + p3);
        acc.x += p0 * xj0.x + p1 * xj1.x + p2 * xj2.x + p3 * xj3.x;
        acc.y += p0 * xj0.y + p1 * xj1.y + p2 * xj2.y + p3 * xj3.y;
        xj0 = y0; aj0 = c0; xj1 = y1; aj1 = c1;
        xj2 = y2; aj2 = c2; xj3 = y3; aj3 = c3;
    }
    float rl = __builtin_amdgcn_rcpf(lsum);
    float ox = acc.x * rl;
    float oy = acc.y * rl;
    // mean over heads: lanes with equal (l&7) hold same channel pair across heads
    ox += __shfl_xor(ox, 8); oy += __shfl_xor(oy, 8);
    ox += __shfl_xor(ox, 16); oy += __shfl_xor(oy, 16);
    ox += __shfl_xor(ox, 32); oy += __shfl_xor(oy, 32);
    int c2 = (lane & 7) * 2;
    float vx = ox * 0.125f + b2[c2];
    float vy = oy * 0.125f + b2[c2 + 1];
    // log_softmax across 16 channels held by the 8-lane group (2 per lane)
    float mx = fmaxf(vx, vy);
    mx = fmaxf(mx, __shfl_xor(mx, 1));
    mx = fmaxf(mx, __shfl_xor(mx, 2));
    mx = fmaxf(mx, __shfl_xor(mx, 4));
    float se = __expf(vx - mx) + __expf(vy - mx);
    se += __shfl_xor(se, 1); se += __shfl_xor(se, 2); se += __shfl_xor(se, 4);
    float ls = __logf(se);
    if (lane < 8)
        ((float2*)out)[(size_t)wid * 8 + lane] = make_float2(vx - mx - ls, vy - mx - ls);
}

// ---------------- host ----------------
extern "C" void kernel_launch(void* const* d_in, const int* in_sizes, int n_in,
                              void* d_out, int out_size, void* d_ws, size_t ws_size,
                              hipStream_t stream) {
    const float* x     = (const float*)d_in[0];
    const int*   ei    = (const int*)d_in[1];
    const float* W1    = (const float*)d_in[2];
    const float* attl1 = (const float*)d_in[3];
    const float* attr1 = (const float*)d_in[4];
    const float* b1    = (const float*)d_in[5];
    const float* W2    = (const float*)d_in[6];
    const float* attl2 = (const float*)d_in[7];
    const float* attr2 = (const float*)d_in[8];
    const float* b2    = (const float*)d_in[9];
    float* out = (float*)d_out;

    char* ws = (char*)d_ws;
    size_t off = 0;
    auto alloc = [&](size_t bytes) {
        size_t o = off;
        off += (bytes + 255) & ~(size_t)255;
        return o;
    };
    size_t o_flag   = alloc(4);
    size_t o_counts = alloc((size_t)N_NODES * 4);
    size_t o_fill   = alloc((size_t)N_NODES * 4);
    size_t o_rowptr = alloc((size_t)(N_NODES + 1) * 4);
    size_t o_bsums  = alloc(1024 * 4);
    size_t o_col    = alloc((size_t)(EPRIME + 8) * 4);   // +8 sentinel pad
    size_t o_h1     = alloc((size_t)N_NODES * 64 * 4);   // (over-alloc; h1 is fp16)
    size_t o_hout   = alloc((size_t)N_NODES * 64 * 4);
    size_t o_h2     = alloc((size_t)N_NODES * 128 * 4);  // (over-alloc; h2 is fp16)
    size_t o_w1f    = alloc((size_t)512 * 64 * 2);       // fp16 swizzled W1

    size_t aldsz = ((size_t)N_NODES * 8 * 4 + 255) & ~(size_t)255;
    // layer-1 att dots alias the h2 region (h2 written later, after attn1 reads these)
    size_t o_ald1 = o_h2;
    size_t o_ard1 = o_h2 + aldsz;
    // layer-2 att dots alias the h1 region (h1 dead after attn1)
    size_t o_ald2 = o_h1;
    size_t o_ard2 = o_h1 + aldsz;

    unsigned* flag = (unsigned*)(ws + o_flag);
    int* counts = (int*)(ws + o_counts);
    int* fill   = (int*)(ws + o_fill);
    int* rowptr = (int*)(ws + o_rowptr);
    int* bsums  = (int*)(ws + o_bsums);
    int* col    = (int*)(ws + o_col);
    __half* h1  = (__half*)(ws + o_h1);
    float* hout = (float*)(ws + o_hout);
    __half2* h2 = (__half2*)(ws + o_h2);
    _Float16* w1f = (_Float16*)(ws + o_w1f);
    float* ald1 = (float*)(ws + o_ald1);
    float* ard1 = (float*)(ws + o_ard1);
    float* ald2 = (float*)(ws + o_ald2);
    float* ard2 = (float*)(ws + o_ard2);

    int nscan = (N_NODES + 1 + 1023) / 1024;  // 99

    hipLaunchKernelGGL(detect_k, dim3(1), dim3(256), 0, stream, (const unsigned*)ei, flag);
    hipLaunchKernelGGL(init_k, dim3((N_NODES + 255) / 256), dim3(256), 0, stream, counts, fill);
    hipLaunchKernelGGL(count_k, dim3((N_EDGES + 255) / 256), dim3(256), 0, stream, ei, flag, counts);
    hipLaunchKernelGGL(scan1_k, dim3(nscan), dim3(256), 0, stream, counts, rowptr, bsums);
    hipLaunchKernelGGL(scan2_k, dim3(1), dim3(64), 0, stream, bsums, nscan);
    hipLaunchKernelGGL(scan3_k, dim3(nscan), dim3(256), 0, stream, rowptr, bsums);
    hipLaunchKernelGGL(scatter_k, dim3((EPRIME + 255) / 256), dim3(256), 0, stream,
                       ei, flag, rowptr, fill, col);
    hipLaunchKernelGGL(w1cvt_k, dim3(128), dim3(256), 0, stream, W1, w1f);
    hipLaunchKernelGGL(gemm1_k, dim3((N_NODES + 63) / 64), dim3(256), 0, stream,
                       x, w1f, attl1, attr1, h1, ald1, ard1);
    hipLaunchKernelGGL(attn1_k, dim3((N_NODES + 3) / 4), dim3(256), 0, stream,
                       h1, rowptr, col, ald1, ard1, b1, hout);
    hipLaunchKernelGGL(gemm2_k, dim3((N_NODES + 31) / 32), dim3(256), 0, stream,
                       hout, W2, attl2, attr2, h2, ald2, ard2);
    hipLaunchKernelGGL(attn2_k, dim3((N_NODES + 3) / 4), dim3(256), 0, stream,
                       h2, rowptr, col, ald2, ard2, b2, out);
}